// Round 1
// baseline (258.723 us; speedup 1.0000x reference)
//
#include <hip/hip_runtime.h>
#include <stdint.h>

// ksparse: per row of 4096x8192 f32, threshold = 513th largest (k=512),
// out = x * (x > thresh). Exact radix-select on the order-preserving uint32
// mapping: ONE 11-bit/2048-bin pass, candidate compaction (~220 survivors),
// three 7-bit/128-bin tail passes scanned by a single wave.
//
// v2: cross-row software pipeline. Each block processes RPB=4 rows with
// double-buffered row registers: loads for row i+1 are issued as soon as
// row i's map/histogram has consumed its buffer, so the select phase
// (scan+compact+tails, ~2-4us of no-memory compute) and the write of row i
// hide the next row's HBM latency and keep the memory pipe busy.
// Output is written with NON-TEMPORAL stores so the 134MB write stream does
// not evict the 128MB input from the 256MB L3 (steady-state reads hit L3).

constexpr int COLS  = 8192;
constexpr int TPB   = 256;
constexpr int EPT   = COLS / TPB;  // 32 elements per thread
constexpr int VPT   = EPT / 4;     // 8 float4 per thread
constexpr int NBIN0 = 2048;        // pass-0 bins (11 bits)
constexpr int CAP   = 2048;        // candidate buffer capacity (reuses replica 1)

typedef float f32x4 __attribute__((ext_vector_type(4)));

__device__ __forceinline__ uint32_t map_f32(uint32_t u) {
  return (u & 0x80000000u) ? ~u : (u | 0x80000000u);
}
__device__ __forceinline__ float unmap_f32(uint32_t m) {
  return __uint_as_float((m & 0x80000000u) ? (m ^ 0x80000000u) : ~m);
}

template <int RPB>
__global__ __launch_bounds__(TPB, 4)
void ksparse_kernel(const float* __restrict__ in, const int* __restrict__ kptr,
                    float* __restrict__ out) {
  __shared__ __align__(16) uint32_t hist[2 * NBIN0]; // 16 KiB: replica0 | replica1 (-> cand)
  __shared__ uint32_t th[3 * 128];                   // tail histograms
  __shared__ uint32_t wtot[4];
  __shared__ uint32_t s_packed;                      // (bin<<14)|above from pass 0
  __shared__ uint32_t s_cnt;                         // candidate count
  __shared__ uint32_t s_sel[3];                      // (digit<<16)|above per tail pass

  const int t    = threadIdx.x;
  const int wave = t >> 6;
  const int lane = t & 63;
  const size_t row0 = (size_t)blockIdx.x * RPB;

  const uint32_t kbase = (uint32_t)(*kptr) + 1u; // rank from top: 513th largest

  float4   v[2][VPT];  // double-buffered raw row data (indices compile-time after unroll)
  uint32_t m[EPT];     // mapped current row (lives until its write)

  // ---- prologue: issue loads for row 0 ----
  {
    const float4* inp = (const float4*)(in + row0 * COLS);
#pragma unroll
    for (int i = 0; i < VPT; ++i) v[0][i] = inp[t + i * TPB];
  }

#pragma unroll
  for (int r = 0; r < RPB; ++r) {
    // ---- zero LDS for this row; overlaps in-flight global loads ----
    // Safe without a leading barrier: everything zeroed here is dead after the
    // previous row's final tail barrier (only s_sel/registers are read after it).
    uint4* h4 = (uint4*)hist;
#pragma unroll
    for (int i = 0; i < 4; ++i) h4[t + i * TPB] = make_uint4(0u, 0u, 0u, 0u);
    th[t] = 0u;
    if (t < 128) th[256 + t] = 0u;
    if (t == 0) { s_packed = 0u; s_cnt = 0u; }
    uint32_t kk = kbase;
    __syncthreads(); // B1: zeroing done

    // ---- pass 0: map + 2048-bin histogram (2 replicas, one per wave-pair) ----
    uint32_t* h = &hist[(wave >> 1) * NBIN0];
#pragma unroll
    for (int i = 0; i < VPT; ++i) {
      m[4 * i + 0] = map_f32(__float_as_uint(v[r & 1][i].x));
      m[4 * i + 1] = map_f32(__float_as_uint(v[r & 1][i].y));
      m[4 * i + 2] = map_f32(__float_as_uint(v[r & 1][i].z));
      m[4 * i + 3] = map_f32(__float_as_uint(v[r & 1][i].w));
      atomicAdd(&h[m[4 * i + 0] >> 21], 1u);
      atomicAdd(&h[m[4 * i + 1] >> 21], 1u);
      atomicAdd(&h[m[4 * i + 2] >> 21], 1u);
      atomicAdd(&h[m[4 * i + 3] >> 21], 1u);
    }

    // ---- issue loads for the NEXT row (buffer just freed by the map above).
    // These stay in flight under the select phase + write below. ----
    if (r + 1 < RPB) {
      const float4* inp = (const float4*)(in + (row0 + (size_t)(r + 1)) * COLS);
#pragma unroll
      for (int i = 0; i < VPT; ++i) v[(r + 1) & 1][i] = inp[t + i * TPB];
    }
    __syncthreads(); // B2: histogram done

    // ---- pass-0 scan: 8 bins/thread, wave suffix, packed argmax ----
    {
      const uint4* hv = (const uint4*)hist;
      uint4 a0 = hv[2 * t], a1 = hv[2 * t + 1];
      uint4 b0 = hv[512 + 2 * t], b1 = hv[512 + 2 * t + 1];
      uint32_t c0 = a0.x + b0.x, c1 = a0.y + b0.y, c2 = a0.z + b0.z, c3 = a0.w + b0.w;
      uint32_t c4 = a1.x + b1.x, c5 = a1.y + b1.y, c6 = a1.z + b1.z, c7 = a1.w + b1.w;
      uint32_t sl[8];
      sl[7] = c7;         sl[6] = sl[7] + c6; sl[5] = sl[6] + c5; sl[4] = sl[5] + c4;
      sl[3] = sl[4] + c3; sl[2] = sl[3] + c2; sl[1] = sl[2] + c1; sl[0] = sl[1] + c0;
      const uint32_t total = sl[0];

      uint32_t s = total;
#pragma unroll
      for (int off = 1; off < 64; off <<= 1) {
        uint32_t tmp = __shfl_down(s, off, 64);
        s += (lane + off < 64) ? tmp : 0u;
      }
      if (lane == 0) wtot[wave] = s;
      __syncthreads(); // B3

      uint32_t hi = 0;
#pragma unroll
      for (int w = 1; w < 4; ++w)
        if (w > wave) hi += wtot[w];
      const uint32_t excl = hi + (s - total);

      int best = -1;
#pragma unroll
      for (int j = 7; j >= 0; --j)
        if (best < 0 && excl + sl[j] >= kk) best = j;
      if (best >= 0) {
        const uint32_t above = excl + ((best < 7) ? sl[best + 1] : 0u);
        atomicMax(&s_packed, ((uint32_t)(t * 8 + best) << 14) | above);
      }
    }
    __syncthreads(); // B4

    const uint32_t pk = s_packed;
    const uint32_t d0 = pk >> 14;
    kk -= (pk & 0x3FFFu);

    // ---- compact candidates (top-11 bits == d0) into dead replica-1 LDS ----
    uint32_t* cand = &hist[NBIN0];
#pragma unroll
    for (int i = 0; i < EPT; ++i) {
      if ((m[i] >> 21) == d0) {
        uint32_t idx = atomicAdd(&s_cnt, 1u);
        if (idx < CAP) cand[idx] = m[i] & 0x1FFFFFu; // low 21 bits
      }
    }
    __syncthreads(); // B5
    const uint32_t Cc = (s_cnt < (uint32_t)CAP) ? s_cnt : (uint32_t)CAP;

    // ---- three 7-bit tail passes over the candidates ----
    uint32_t tpref = 0;
#pragma unroll 1
    for (int j = 0; j < 3; ++j) {
      const int dsh = 14 - 7 * j;
      uint32_t* thj = &th[j * 128];
      for (uint32_t idx = t; idx < Cc; idx += TPB) {
        const uint32_t c = cand[idx];
        const bool ok = (j == 0) || ((c >> (dsh + 7)) == tpref);
        if (ok) atomicAdd(&thj[(c >> dsh) & 127u], 1u);
      }
      __syncthreads(); // tail histogram done

      if (wave == 0) { // single-wave 128-bin suffix scan + digit pick
        uint32_t a = thj[lane], b = thj[64 + lane];
        uint32_t sb = b, sa = a;
#pragma unroll
        for (int off = 1; off < 64; off <<= 1) {
          uint32_t t1 = __shfl_down(sb, off, 64);
          uint32_t t2 = __shfl_down(sa, off, 64);
          const bool inr = (lane + off < 64);
          sb += inr ? t1 : 0u;
          sa += inr ? t2 : 0u;
        }
        const uint32_t tb = __shfl(sb, 0, 64); // total of bins 64..127
        sa += tb;
        const unsigned long long mb = __ballot(sb >= kk);
        uint32_t d, ab;
        if (mb) {
          const int hb = 63 - __builtin_clzll(mb);
          const uint32_t nx = __shfl(sb, (hb + 1) & 63, 64);
          d = 64 + hb;
          ab = (hb == 63) ? 0u : nx;
        } else {
          const unsigned long long ma = __ballot(sa >= kk); // nonzero by invariant
          const int ha = 63 - __builtin_clzll(ma);
          const uint32_t nx = __shfl(sa, (ha + 1) & 63, 64);
          d = (uint32_t)ha;
          ab = (ha == 63) ? tb : nx;
        }
        if (lane == 0) s_sel[j] = (d << 16) | ab;
      }
      __syncthreads(); // selection published

      const uint32_t sel = s_sel[j];
      tpref = (tpref << 7) | (sel >> 16);
      kk -= (sel & 0xFFFFu);
    }

    const uint32_t T = (d0 << 21) | tpref; // exact mapped bits of rank-(k+1) elem

    // ---- masked write: keep strictly greater than threshold.
    // Non-temporal: the output stream is never re-read; keep it from
    // displacing the input in L2/L3. ----
    f32x4* op = (f32x4*)(out + (row0 + (size_t)r) * COLS);
#pragma unroll
    for (int i = 0; i < VPT; ++i) {
      f32x4 w;
      uint32_t mm;
      mm = m[4 * i + 0]; w.x = (mm > T) ? unmap_f32(mm) : 0.0f;
      mm = m[4 * i + 1]; w.y = (mm > T) ? unmap_f32(mm) : 0.0f;
      mm = m[4 * i + 2]; w.z = (mm > T) ? unmap_f32(mm) : 0.0f;
      mm = m[4 * i + 3]; w.w = (mm > T) ? unmap_f32(mm) : 0.0f;
      __builtin_nontemporal_store(w, &op[t + i * TPB]);
    }
  }
}

extern "C" void kernel_launch(void* const* d_in, const int* in_sizes, int n_in,
                              void* d_out, int out_size, void* d_ws, size_t ws_size,
                              hipStream_t stream) {
  const float* in  = (const float*)d_in[0];
  const int*   k   = (const int*)d_in[1];
  float*       out = (float*)d_out;
  int rows = in_sizes[0] / COLS;
  if (rows < 1) rows = 1;
  if ((rows & 3) == 0) {
    ksparse_kernel<4><<<rows / 4, TPB, 0, stream>>>(in, k, out);
  } else {
    ksparse_kernel<1><<<rows, TPB, 0, stream>>>(in, k, out);
  }
}

// Round 2
// 246.996 us; speedup vs baseline: 1.0475x; 1.0475x over previous
//
#include <hip/hip_runtime.h>
#include <stdint.h>

// ksparse: per row of 4096x8192 f32, threshold = 513th largest (k=512),
// out = x * (x > thresh). Exact radix-select on the order-preserving uint32
// mapping: ONE 11-bit/2048-bin pass, candidate compaction (~220 survivors),
// three 7-bit/128-bin tail passes scanned by a single wave.
//
// v3: fuse RPB=2 rows per block HORIZONTALLY (not pipelined -- __syncthreads
// drains vmcnt(0) on gfx950, so cross-phase prefetch is impossible; v2 proved
// that). Both rows' loads issue up front (64KB in flight before the one
// unavoidable drain at B1), and every phase handles both rows between the
// SAME barriers: barrier count per row halves (11 -> 5.5), LDS zeroing per
// row halves, and the two single-wave tail scans run concurrently (wave 0
// scans row A while wave 1 scans row B). Plain stores (NT grew WRITE_SIZE).
// __launch_bounds__(256,4) caps VGPR at 128 (expect ~110, no spill).

constexpr int COLS  = 8192;
constexpr int TPB   = 256;
constexpr int EPT   = COLS / TPB;  // 32 elements per thread per row
constexpr int VPT   = EPT / 4;     // 8 float4 per thread per row
constexpr int NBIN0 = 2048;        // pass-0 bins (11 bits)
constexpr int CAP   = 2048;        // candidate buffer capacity per row

__device__ __forceinline__ uint32_t map_f32(uint32_t u) {
  return (u & 0x80000000u) ? ~u : (u | 0x80000000u);
}
__device__ __forceinline__ float unmap_f32(uint32_t m) {
  return __uint_as_float((m & 0x80000000u) ? (m ^ 0x80000000u) : ~m);
}

template <int RPB>
__global__ __launch_bounds__(TPB, 4)
void ksparse_kernel(const float* __restrict__ in, const int* __restrict__ kptr,
                    float* __restrict__ out) {
  constexpr int NH = (RPB > 1) ? RPB : 2; // row r hist at hist[r*NBIN0]; cand reuses dead hist
  __shared__ __align__(16) uint32_t hist[NH * NBIN0];
  __shared__ uint32_t th[RPB * 3 * 128];  // tail histograms per (row, pass)
  __shared__ uint32_t wtot[RPB][4];
  __shared__ uint32_t s_packed[RPB];      // (bin<<14)|above from pass 0
  __shared__ uint32_t s_cnt[RPB];         // candidate counts
  __shared__ uint32_t s_sel[RPB][3];      // (digit<<16)|above per tail pass

  const int t    = threadIdx.x;
  const int wave = t >> 6;
  const int lane = t & 63;
  const size_t rowbase = (size_t)blockIdx.x * RPB * COLS;

  // ---- issue ALL global loads (both rows) before anything else ----
  const float4* inp = (const float4*)(in + rowbase);
  float4 v[RPB][VPT];
#pragma unroll
  for (int r = 0; r < RPB; ++r)
#pragma unroll
    for (int i = 0; i < VPT; ++i)
      v[r][i] = inp[r * (COLS / 4) + t + i * TPB];

  // ---- zero LDS; overlaps the in-flight load latency ----
  uint4* h4 = (uint4*)hist;
#pragma unroll
  for (int i = 0; i < NH * NBIN0 / 4 / TPB; ++i)
    h4[t + i * TPB] = make_uint4(0u, 0u, 0u, 0u);
#pragma unroll
  for (int i = 0; i < (RPB * 384 + TPB - 1) / TPB; ++i) {
    const int idx = t + i * TPB;
    if (idx < RPB * 384) th[idx] = 0u;
  }
  if (t < RPB) { s_packed[t] = 0u; s_cnt[t] = 0u; }
  const uint32_t kbase = (uint32_t)(*kptr) + 1u; // rank from top: 513th largest
  __syncthreads(); // B1: zeroing done (drains loads -- unavoidable on gfx950)

  // ---- pass 0: map + per-row 2048-bin histogram ----
  uint32_t m[RPB][EPT];
#pragma unroll
  for (int r = 0; r < RPB; ++r) {
    uint32_t* h = &hist[r * NBIN0];
#pragma unroll
    for (int i = 0; i < VPT; ++i) {
      m[r][4 * i + 0] = map_f32(__float_as_uint(v[r][i].x));
      m[r][4 * i + 1] = map_f32(__float_as_uint(v[r][i].y));
      m[r][4 * i + 2] = map_f32(__float_as_uint(v[r][i].z));
      m[r][4 * i + 3] = map_f32(__float_as_uint(v[r][i].w));
      atomicAdd(&h[m[r][4 * i + 0] >> 21], 1u);
      atomicAdd(&h[m[r][4 * i + 1] >> 21], 1u);
      atomicAdd(&h[m[r][4 * i + 2] >> 21], 1u);
      atomicAdd(&h[m[r][4 * i + 3] >> 21], 1u);
    }
  }
  __syncthreads(); // B2: histograms done

  // ---- pass-0 scan, both rows between the same two barriers ----
  uint32_t kk[RPB];
  uint32_t sl0[RPB];      // this thread's 8-bin total
  uint32_t ssum[RPB];     // wave suffix sum from this lane
  uint4    sva0[RPB], sva1[RPB]; // raw bin quads, re-scanned after B3
#pragma unroll
  for (int r = 0; r < RPB; ++r) {
    kk[r] = kbase;
    const uint4* hv = (const uint4*)&hist[r * NBIN0];
    const uint4 a0 = hv[2 * t], a1 = hv[2 * t + 1];
    sva0[r] = a0; sva1[r] = a1;
    const uint32_t total = a0.x + a0.y + a0.z + a0.w + a1.x + a1.y + a1.z + a1.w;
    sl0[r] = total;

    uint32_t s = total;
#pragma unroll
    for (int off = 1; off < 64; off <<= 1) {
      const uint32_t tmp = __shfl_down(s, off, 64);
      s += (lane + off < 64) ? tmp : 0u;
    }
    ssum[r] = s;
    if (lane == 0) wtot[r][wave] = s;
  }
  __syncthreads(); // B3: wave totals published

#pragma unroll
  for (int r = 0; r < RPB; ++r) {
    uint32_t hi = 0;
#pragma unroll
    for (int w = 1; w < 4; ++w)
      if (w > wave) hi += wtot[r][w];
    const uint32_t excl = hi + (ssum[r] - sl0[r]);

    const uint4 a0 = sva0[r], a1 = sva1[r];
    uint32_t sl[8];
    sl[7] = a1.w;         sl[6] = sl[7] + a1.z; sl[5] = sl[6] + a1.y; sl[4] = sl[5] + a1.x;
    sl[3] = sl[4] + a0.w; sl[2] = sl[3] + a0.z; sl[1] = sl[2] + a0.y; sl[0] = sl[1] + a0.x;

    int b = -1;
#pragma unroll
    for (int j = 7; j >= 0; --j)
      if (b < 0 && excl + sl[j] >= kk[r]) b = j;
    if (b >= 0) {
      const uint32_t above = excl + ((b < 7) ? sl[b + 1] : 0u);
      atomicMax(&s_packed[r], ((uint32_t)(t * 8 + b) << 14) | above);
    }
  }
  __syncthreads(); // B4: selections published

  // ---- compact candidates into hist (dead after scan) ----
  uint32_t d0[RPB];
#pragma unroll
  for (int r = 0; r < RPB; ++r) {
    const uint32_t pk = s_packed[r];
    d0[r] = pk >> 14;
    kk[r] -= (pk & 0x3FFFu);
    uint32_t* cand = &hist[(RPB == 1 ? 1 : r) * NBIN0];
#pragma unroll
    for (int i = 0; i < EPT; ++i) {
      if ((m[r][i] >> 21) == d0[r]) {
        const uint32_t idx = atomicAdd(&s_cnt[r], 1u);
        if (idx < CAP) cand[idx] = m[r][i] & 0x1FFFFFu; // low 21 bits
      }
    }
  }
  __syncthreads(); // B5: compaction done
  uint32_t Cc[RPB];
#pragma unroll
  for (int r = 0; r < RPB; ++r)
    Cc[r] = (s_cnt[r] < (uint32_t)CAP) ? s_cnt[r] : (uint32_t)CAP;

  // ---- three 7-bit tail passes; rows share barriers, scans in parallel waves ----
  uint32_t tpref[RPB];
#pragma unroll
  for (int r = 0; r < RPB; ++r) tpref[r] = 0;

#pragma unroll 1
  for (int j = 0; j < 3; ++j) {
    const int dsh = 14 - 7 * j;
#pragma unroll
    for (int r = 0; r < RPB; ++r) {
      uint32_t* thj = &th[(r * 3 + j) * 128];
      uint32_t* cand = &hist[(RPB == 1 ? 1 : r) * NBIN0];
      for (uint32_t idx = t; idx < Cc[r]; idx += TPB) {
        const uint32_t c = cand[idx];
        const bool ok = (j == 0) || ((c >> (dsh + 7)) == tpref[r]);
        if (ok) atomicAdd(&thj[(c >> dsh) & 127u], 1u);
      }
    }
    __syncthreads(); // tail histograms done

    if (wave < RPB) { // wave r scans row r concurrently
      uint32_t kw = 0;
      uint32_t* thj = &th[j * 128];
#pragma unroll
      for (int r = 0; r < RPB; ++r)
        if (wave == r) { kw = kk[r]; thj = &th[(r * 3 + j) * 128]; }

      const uint32_t a = thj[lane], b = thj[64 + lane];
      uint32_t sb = b, sa = a;
#pragma unroll
      for (int off = 1; off < 64; off <<= 1) {
        const uint32_t t1 = __shfl_down(sb, off, 64);
        const uint32_t t2 = __shfl_down(sa, off, 64);
        const bool inr = (lane + off < 64);
        sb += inr ? t1 : 0u;
        sa += inr ? t2 : 0u;
      }
      const uint32_t tb = __shfl(sb, 0, 64); // total of bins 64..127
      sa += tb;
      const unsigned long long mb = __ballot(sb >= kw);
      uint32_t d, ab;
      if (mb) {
        const int hb = 63 - __builtin_clzll(mb);
        const uint32_t nx = __shfl(sb, (hb + 1) & 63, 64);
        d = 64 + (uint32_t)hb;
        ab = (hb == 63) ? 0u : nx;
      } else {
        const unsigned long long ma = __ballot(sa >= kw); // nonzero by invariant
        const int ha = 63 - __builtin_clzll(ma);
        const uint32_t nx = __shfl(sa, (ha + 1) & 63, 64);
        d = (uint32_t)ha;
        ab = (ha == 63) ? tb : nx;
      }
      if (lane == 0) s_sel[wave][j] = (d << 16) | ab;
    }
    __syncthreads(); // selections published

#pragma unroll
    for (int r = 0; r < RPB; ++r) {
      const uint32_t sel = s_sel[r][j];
      tpref[r] = (tpref[r] << 7) | (sel >> 16);
      kk[r] -= (sel & 0xFFFFu);
    }
  }

  // ---- masked writes: keep strictly greater than threshold ----
  float4* op = (float4*)(out + rowbase);
#pragma unroll
  for (int r = 0; r < RPB; ++r) {
    const uint32_t T = (d0[r] << 21) | tpref[r]; // exact mapped bits of rank-(k+1)
#pragma unroll
    for (int i = 0; i < VPT; ++i) {
      float4 w;
      uint32_t mm;
      mm = m[r][4 * i + 0]; w.x = (mm > T) ? unmap_f32(mm) : 0.0f;
      mm = m[r][4 * i + 1]; w.y = (mm > T) ? unmap_f32(mm) : 0.0f;
      mm = m[r][4 * i + 2]; w.z = (mm > T) ? unmap_f32(mm) : 0.0f;
      mm = m[r][4 * i + 3]; w.w = (mm > T) ? unmap_f32(mm) : 0.0f;
      op[r * (COLS / 4) + t + i * TPB] = w;
    }
  }
}

extern "C" void kernel_launch(void* const* d_in, const int* in_sizes, int n_in,
                              void* d_out, int out_size, void* d_ws, size_t ws_size,
                              hipStream_t stream) {
  const float* in  = (const float*)d_in[0];
  const int*   k   = (const int*)d_in[1];
  float*       out = (float*)d_out;
  int rows = in_sizes[0] / COLS;
  if (rows < 1) rows = 1;
  if ((rows & 1) == 0) {
    ksparse_kernel<2><<<rows / 2, TPB, 0, stream>>>(in, k, out);
  } else {
    ksparse_kernel<1><<<rows, TPB, 0, stream>>>(in, k, out);
  }
}